// Round 14
// baseline (42.202 us; speedup 1.0000x reference)
//
#include <hip/hip_runtime.h>

#define NPERS 64
#define NJOINT 15
#define NDEPTH 128
#define BIGF 100000.0f
#define EPSF 1e-8f
#define INFF 3.0e38f

// j-outer / q-inner formulation (R13 post-mortem): the q-outer form kept a
// 60-float X/Y tile live across the q-loop and the allocator ALWAYS spilled
// it (R9-R13, 64-128 VGPR caps). Here the live set is 32 accumulators
// (16 q x 2 persons) + 12 streamed coef floats + scalars ~= 95 regs < 128
// by construction. X_j/Y_j are recomputed per j (28 VALU) instead of cached.
// Coefficients are transposed to [j][q*3] so a 4-candidate subgroup is
// 3 contiguous ds_read_b128. npv-skip via contiguous per-wave q-slices.
__global__ __launch_bounds__(256, 4)
void pose_match_kernel(
    const float* __restrict__ poses_3d,   // (B,NP,NJ,ND,3)
    const float* __restrict__ p2d,        // (B,NP,NJ,2)
    const float* __restrict__ vis,        // (B,NP,NJ)
    const int*   __restrict__ nper,       // (B,)
    const float* __restrict__ Rm,         // (B,3,3)
    const float* __restrict__ Tm,         // (B,3)
    const float* __restrict__ fm,         // (B,2)
    const float* __restrict__ cm,         // (B,2)
    const float* __restrict__ iw_,        // (B,)
    const float* __restrict__ ih_,        // (B,)
    float* __restrict__ out)              // (B,NP,NJ,ND)
{
    const int b    = blockIdx.x >> 6;     // 64 blocks per batch: 32 pp x 2 dh
    const int rem  = blockIdx.x & 63;
    const int pp   = rem >> 1;
    const int dh   = rem & 1;
    const int p0   = pp * 2;
    const int tid  = threadIdx.x;
    const int wv   = tid >> 6;            // wave id 0..3 = contiguous q-slice
    const int lane = tid & 63;
    const int d    = dh * 64 + lane;      // this thread's depth bin

    __shared__ float4 sq[NPERS][NJOINT];     // {vis, rx, ry, _} (epilogue)
    __shared__ float4 sco2[NJOINT][48];      // [j][q*3]/4: (w,wx,wy) per q
    __shared__ float  sc_c[NPERS];           // c term per q
    __shared__ float  bvred[4][2][64];       // [wave][person][lane]
    __shared__ int    bqred[4][2][64];

    // ---- stage raw candidate data ----
    for (int i = tid; i < NPERS * NJOINT; i += 256) {
        int q = i / NJOINT, j = i % NJOINT;
        float v  = vis[(b * NPERS + q) * NJOINT + j];
        float rx = p2d[((b * NPERS + q) * NJOINT + j) * 2 + 0];
        float ry = p2d[((b * NPERS + q) * NJOINT + j) * 2 + 1];
        sq[q][j] = make_float4(v, rx, ry, 0.0f);
    }
    __syncthreads();

    // ---- fold coefficients, transposed store [j][q*3] ----
    // w=vis*inv; wx=2*vis*rx*inv; wy=2*vis*ry*inv; c=(sum (rx^2+ry^2)vis)*inv
    if (tid < NPERS) {
        const int q = tid;
        float vs = 0.0f, t2 = 0.0f;
        #pragma unroll
        for (int j = 0; j < NJOINT; ++j) {
            float4 s = sq[q][j];
            vs += s.x;
            t2 = fmaf(s.y * s.y + s.z * s.z, s.x, t2);
        }
        float inv = 1.0f / (vs + EPSF);
        #pragma unroll
        for (int j = 0; j < NJOINT; ++j) {
            float4 s = sq[q][j];
            float* row = (float*)&sco2[j][0];
            row[q * 3 + 0] = s.x * inv;                 // 3q mod 32: 2-way max
            row[q * 3 + 1] = 2.0f * s.x * s.y * inv;
            row[q * 3 + 2] = 2.0f * s.x * s.z * inv;
        }
        sc_c[q] = t2 * inv;
    }
    __syncthreads();

    // ---- camera params (wave-uniform) ----
    const float R00 = Rm[b*9+0], R01 = Rm[b*9+1], R02 = Rm[b*9+2];
    const float R10 = Rm[b*9+3], R11 = Rm[b*9+4], R12 = Rm[b*9+5];
    const float R20 = Rm[b*9+6], R21 = Rm[b*9+7], R22 = Rm[b*9+8];
    const float T0 = Tm[b*3+0], T1 = Tm[b*3+1], T2 = Tm[b*3+2];
    const float fx = fm[b*2+0], fy = fm[b*2+1];
    const float cx = cm[b*2+0], cy = cm[b*2+1];
    const float iwm1 = iw_[b] - 1.0f;
    const float ihm1 = ih_[b] - 1.0f;
    const int   npv  = nper[b];

    // this wave's slice: q in [q0, q0+nv)
    const int q0 = wv * 16;
    const int nv = min(max(npv - q0, 0), 16);

    // per-person base pointers (element offset per j is j*NDEPTH*3)
    const float* pA = poses_3d + ((size_t)(b * NPERS + p0    ) * NJOINT * NDEPTH + d) * 3;
    const float* pB = poses_3d + ((size_t)(b * NPERS + p0 + 1) * NJOINT * NDEPTH + d) * 3;

    // ---- j-outer accumulation: 32 static accumulators ----
    float acc[2][16];
    #pragma unroll
    for (int k = 0; k < 16; ++k) { acc[0][k] = 0.0f; acc[1][k] = 0.0f; }

    #pragma unroll 1
    for (int j = 0; j < NJOINT; ++j) {
        // project joint j for both persons (transient, ~4 live regs out)
        const int off = j * NDEPTH * 3;
        float X0, Y0, X1, Y1;
        {
            float a0 = pA[off + 0] - T0;
            float a1 = pA[off + 1] - T1;
            float a2 = pA[off + 2] - T2;
            float xc0 = R00 * a0 + R01 * a1 + R02 * a2;
            float xc1 = R10 * a0 + R11 * a1 + R12 * a2;
            float xc2 = R20 * a0 + R21 * a1 + R22 * a2;
            float r   = __builtin_amdgcn_rcpf(xc2);
            X0 = fmaf(fx * xc0, r, cx);
            Y0 = fmaf(fy * xc1, r, cy);
        }
        {
            float a0 = pB[off + 0] - T0;
            float a1 = pB[off + 1] - T1;
            float a2 = pB[off + 2] - T2;
            float xc0 = R00 * a0 + R01 * a1 + R02 * a2;
            float xc1 = R10 * a0 + R11 * a1 + R12 * a2;
            float xc2 = R20 * a0 + R21 * a1 + R22 * a2;
            float r   = __builtin_amdgcn_rcpf(xc2);
            X1 = fmaf(fx * xc0, r, cx);
            Y1 = fmaf(fy * xc1, r, cy);
        }

        // stream coefficients: 4-candidate subgroups, 3 x ds_read_b128 each
        #pragma unroll
        for (int g = 0; g < 4; ++g) {
            if (g * 4 < nv) {                     // wave-uniform skip
                float4 r0 = sco2[j][wv * 12 + g * 3 + 0];
                float4 r1 = sco2[j][wv * 12 + g * 3 + 1];
                float4 r2 = sco2[j][wv * 12 + g * 3 + 2];
                // (w,wx,wy) for the 4 candidates of this subgroup
#define ACC1(K, W, WX, WY)                                                    \
                {                                                             \
                    float u;                                                  \
                    u = fmaf((W), X0, -(WX));                                 \
                    acc[0][g * 4 + K] = fmaf(X0, u, acc[0][g * 4 + K]);       \
                    u = fmaf((W), Y0, -(WY));                                 \
                    acc[0][g * 4 + K] = fmaf(Y0, u, acc[0][g * 4 + K]);       \
                    u = fmaf((W), X1, -(WX));                                 \
                    acc[1][g * 4 + K] = fmaf(X1, u, acc[1][g * 4 + K]);       \
                    u = fmaf((W), Y1, -(WY));                                 \
                    acc[1][g * 4 + K] = fmaf(Y1, u, acc[1][g * 4 + K]);       \
                }
                ACC1(0, r0.x, r0.y, r0.z)
                ACC1(1, r0.w, r1.x, r1.y)
                ACC1(2, r1.z, r1.w, r2.x)
                ACC1(3, r2.y, r2.z, r2.w)
#undef ACC1
            }
        }
    }

    // ---- per-wave argmin over the slice (ascending k, strict <) ----
    float bv0, bv1;
    int   bq0, bq1;
    if (npv < NPERS) { bv0 = bv1 = BIGF; bq0 = bq1 = npv; }
    else             { bv0 = bv1 = INFF; bq0 = bq1 = 0;   }
    #pragma unroll
    for (int k = 0; k < 16; ++k) {
        if (k < nv) {                              // wave-uniform
            float cterm = sc_c[q0 + k];
            float d0 = acc[0][k] + cterm;
            float d1 = acc[1][k] + cterm;
            if (d0 < bv0) { bv0 = d0; bq0 = q0 + k; }
            if (d1 < bv1) { bv1 = d1; bq1 = q0 + k; }
        }
    }
    bvred[wv][0][lane] = bv0;  bqred[wv][0][lane] = bq0;
    bvred[wv][1][lane] = bv1;  bqred[wv][1][lane] = bq1;
    __syncthreads();

    // ---- waves 0,1 finish person 0,1: combine by (value,q) + epilogue ----
#define EPILOGUE(PI, PPTR)                                                    \
    if (wv == PI) {                                                           \
        float bestv = bvred[0][PI][lane];                                     \
        int   bestq = bqred[0][PI][lane];                                     \
        _Pragma("unroll")                                                     \
        for (int k = 1; k < 4; ++k) {                                         \
            float v  = bvred[k][PI][lane];                                    \
            int   qq = bqred[k][PI][lane];                                    \
            if (v < bestv || (v == bestv && qq < bestq)) {                    \
                bestv = v; bestq = qq;                                        \
            }                                                                 \
        }                                                                     \
        const int obase = ((b * NPERS + p0 + PI) * NJOINT) * NDEPTH + d;      \
        _Pragma("unroll")                                                     \
        for (int j = 0; j < NJOINT; ++j) {                                    \
            const int off = j * NDEPTH * 3;                                   \
            float a0 = PPTR[off + 0] - T0;                                    \
            float a1 = PPTR[off + 1] - T1;                                    \
            float a2 = PPTR[off + 2] - T2;                                    \
            float xc0 = R00 * a0 + R01 * a1 + R02 * a2;                       \
            float xc1 = R10 * a0 + R11 * a1 + R12 * a2;                       \
            float xc2 = R20 * a0 + R21 * a1 + R22 * a2;                       \
            float r   = __builtin_amdgcn_rcpf(xc2);                           \
            float xx  = fmaf(fx * xc0, r, cx);                                \
            float yy  = fmaf(fy * xc1, r, cy);                                \
            float4 v = sq[bestq][j];                                          \
            float dx = xx - v.y;                                              \
            float dy = yy - v.z;                                              \
            float md = fmaf(dx, dx, dy * dy);                                 \
            float sc = __expf(-md * (1.0f / 225.0f));                         \
            float inb = (xx >= 0.0f && yy >= 0.0f &&                          \
                         xx <= iwm1 && yy <= ihm1) ? 1.0f : 0.0f;             \
            out[obase + j * NDEPTH] = sc * inb * v.x;                         \
        }                                                                     \
    }

    EPILOGUE(0, pA)
    EPILOGUE(1, pB)
#undef EPILOGUE
}

extern "C" void kernel_launch(void* const* d_in, const int* in_sizes, int n_in,
                              void* d_out, int out_size, void* d_ws, size_t ws_size,
                              hipStream_t stream) {
    const float* poses_3d = (const float*)d_in[0];
    const float* p2d      = (const float*)d_in[1];
    const float* vis      = (const float*)d_in[2];
    const int*   nper     = (const int*)d_in[3];
    const float* Rm       = (const float*)d_in[4];
    const float* Tm       = (const float*)d_in[5];
    const float* fm       = (const float*)d_in[6];
    const float* cm       = (const float*)d_in[7];
    const float* iw       = (const float*)d_in[8];
    const float* ih       = (const float*)d_in[9];
    float* out = (float*)d_out;

    const int B = in_sizes[3];  // num_persons_ref has B elements
    dim3 grid(B * 64);          // (b, person-pair, depth-half)
    dim3 block(256);            // 4 waves = 4 contiguous q-slices
    pose_match_kernel<<<grid, block, 0, stream>>>(
        poses_3d, p2d, vis, nper, Rm, Tm, fm, cm, iw, ih, out);
}